// Round 9
// baseline (281.349 us; speedup 1.0000x reference)
//
#include <hip/hip_runtime.h>
#include <math.h>

#define D_MODEL 2048
#define KB_ 64
#define NCHUNK 32

typedef __bf16 bf16;
typedef __attribute__((ext_vector_type(8))) __bf16 bf16x8;
typedef __attribute__((ext_vector_type(4))) __bf16 bf16x4;
typedef __attribute__((ext_vector_type(4))) float f32x4;

// ---- workspace layout (float offsets) ----
#define OFF_S      0                            // bufS [32][64][2048]
#define OFF_F      (32 * 64 * 2048)             // bufF [32][64][2048]
#define OFF_C      (2 * 32 * 64 * 2048)         // merged coeffs [32][64][2048]
#define OFF_NORMS  (3 * 32 * 64 * 2048)         // [32][64]
#define OFF_VR     (OFF_NORMS + 2048)           // [2048]
#define OFF_VI     (OFF_VR + 2048)              // [2048]
#define OFF_DSQ    (OFF_VI + 2048)              // [64]  (vr|vi|dsq contiguous)

// ---------------------------------------------------------------------------
// K1: single-pass chunk projection (each scan byte staged ONCE).
// Block (dt, j), j in [0,33):
//   j<32 : stage chunk_j (batch-mean of scan rows [j*256,(j+1)*256), d-tile dt)
//          bufS[j]   = A_hi @ chunk_j     (window j, second half)
//          bufF[j+1] = A_lo @ chunk_j     (window j+1, first half; skip j=31)
//   j=32 : stage buf[256:512) -> bufF[0] = A_lo @ buf_tail
// Block (0,0) zeroes vr|vi|dsq for K2's atomics (stream-ordered, safe).
// ---------------------------------------------------------------------------
__device__ __forceinline__ void load_stage(
    const float* __restrict__ scan, const float* __restrict__ buf,
    int j, int nb, int n0, int dcol, float4* ra, float4* rb)
{
  if (j == 32) {
    const float* bp = buf + (256 + nb * 64 + n0) * 2048 + dcol;
#pragma unroll
    for (int i = 0; i < 4; ++i) { ra[i] = *(const float4*)(bp + i * 2048); rb[i] = ra[i]; }
  } else {
    const float* p0 = scan + (j * 256 + nb * 64 + n0) * 2048 + dcol;
    const float* p1 = p0 + 8192 * 2048;
#pragma unroll
    for (int i = 0; i < 4; ++i) {
      ra[i] = *(const float4*)(p0 + i * 2048);
      rb[i] = *(const float4*)(p1 + i * 2048);
    }
  }
}

__device__ __forceinline__ void store_stage(
    bf16* Bsbuf, int n0, int d4, const float4* ra, const float4* rb)
{
  float4 m0 = make_float4(0.5f * (ra[0].x + rb[0].x), 0.5f * (ra[0].y + rb[0].y),
                          0.5f * (ra[0].z + rb[0].z), 0.5f * (ra[0].w + rb[0].w));
  float4 m1 = make_float4(0.5f * (ra[1].x + rb[1].x), 0.5f * (ra[1].y + rb[1].y),
                          0.5f * (ra[1].z + rb[1].z), 0.5f * (ra[1].w + rb[1].w));
  float4 m2 = make_float4(0.5f * (ra[2].x + rb[2].x), 0.5f * (ra[2].y + rb[2].y),
                          0.5f * (ra[2].z + rb[2].z), 0.5f * (ra[2].w + rb[2].w));
  float4 m3 = make_float4(0.5f * (ra[3].x + rb[3].x), 0.5f * (ra[3].y + rb[3].y),
                          0.5f * (ra[3].z + rb[3].z), 0.5f * (ra[3].w + rb[3].w));
  bf16x4 e0 = {(bf16)m0.x, (bf16)m1.x, (bf16)m2.x, (bf16)m3.x};
  bf16x4 e1 = {(bf16)m0.y, (bf16)m1.y, (bf16)m2.y, (bf16)m3.y};
  bf16x4 e2 = {(bf16)m0.z, (bf16)m1.z, (bf16)m2.z, (bf16)m3.z};
  bf16x4 e3 = {(bf16)m0.w, (bf16)m1.w, (bf16)m2.w, (bf16)m3.w};
  *(bf16x4*)(Bsbuf + (d4 + 0) * 72 + n0) = e0;
  *(bf16x4*)(Bsbuf + (d4 + 1) * 72 + n0) = e1;
  *(bf16x4*)(Bsbuf + (d4 + 2) * 72 + n0) = e2;
  *(bf16x4*)(Bsbuf + (d4 + 3) * 72 + n0) = e3;
}

__global__ __launch_bounds__(256, 4) void k1_part(
    const float* __restrict__ scan, const float* __restrict__ buf,
    const float* __restrict__ cheby, float* __restrict__ bufS,
    float* __restrict__ bufF, float* __restrict__ vzero)
{
  __shared__ bf16 Bs[2][64 * 72];

  const int t = threadIdx.x;
  const int dt = blockIdx.x;     // 0..31 d-tile
  const int j  = blockIdx.y;     // 0..32 chunk (32 = buf tail)
  const int w = t >> 6, lane = t & 63;
  const int quad = lane >> 4, r16 = lane & 15;
  const int d0 = dt * 64;
  const int n0 = (t >> 4) * 4;
  const int d4 = (t & 15) * 4;
  const int dcol = d0 + d4;

  if (dt == 0 && j == 0) {
    for (int i = t; i < 4160; i += 256) vzero[i] = 0.f;   // vr | vi | dsq
  }

  f32x4 accS[4], accF[4];
#pragma unroll
  for (int tn = 0; tn < 4; ++tn) {
    accS[tn] = (f32x4){0.f, 0.f, 0.f, 0.f};
    accF[tn] = (f32x4){0.f, 0.f, 0.f, 0.f};
  }

  float4 ra[4], rb[4];
  load_stage(scan, buf, j, 0, n0, dcol, ra, rb);
  store_stage(Bs[0], n0, d4, ra, rb);
  __syncthreads();

  for (int nb = 0; nb < 4; ++nb) {
    if (nb < 3) load_stage(scan, buf, j, nb + 1, n0, dcol, ra, rb);

    // A-fragments: cheby row (band), cols nb*64.. (A_lo) and 256+nb*64.. (A_hi)
    const float* ab = cheby + (w * 16 + r16) * 512 + nb * 64 + quad * 8;
    float4 f0 = *(const float4*)(ab);
    float4 f1 = *(const float4*)(ab + 4);
    float4 f2 = *(const float4*)(ab + 32);
    float4 f3 = *(const float4*)(ab + 36);
    float4 g0 = *(const float4*)(ab + 256);
    float4 g1 = *(const float4*)(ab + 260);
    float4 g2 = *(const float4*)(ab + 288);
    float4 g3 = *(const float4*)(ab + 292);
    bf16x8 aF[2] = {{(bf16)f0.x, (bf16)f0.y, (bf16)f0.z, (bf16)f0.w,
                     (bf16)f1.x, (bf16)f1.y, (bf16)f1.z, (bf16)f1.w},
                    {(bf16)f2.x, (bf16)f2.y, (bf16)f2.z, (bf16)f2.w,
                     (bf16)f3.x, (bf16)f3.y, (bf16)f3.z, (bf16)f3.w}};
    bf16x8 aS[2] = {{(bf16)g0.x, (bf16)g0.y, (bf16)g0.z, (bf16)g0.w,
                     (bf16)g1.x, (bf16)g1.y, (bf16)g1.z, (bf16)g1.w},
                    {(bf16)g2.x, (bf16)g2.y, (bf16)g2.z, (bf16)g2.w,
                     (bf16)g3.x, (bf16)g3.y, (bf16)g3.z, (bf16)g3.w}};

    const bf16* bsr = Bs[nb & 1];
#pragma unroll
    for (int ks = 0; ks < 2; ++ks) {
#pragma unroll
      for (int tn = 0; tn < 4; ++tn) {
        bf16x8 bfr = *(const bf16x8*)(bsr + (tn * 16 + r16) * 72 + ks * 32 + quad * 8);
        accS[tn] = __builtin_amdgcn_mfma_f32_16x16x32_bf16(aS[ks], bfr, accS[tn], 0, 0, 0);
        accF[tn] = __builtin_amdgcn_mfma_f32_16x16x32_bf16(aF[ks], bfr, accF[tn], 0, 0, 0);
      }
    }

    if (nb < 3) store_stage(Bs[(nb + 1) & 1], n0, d4, ra, rb);
    __syncthreads();
  }

  // epilogue: scale + partial stores (no nsq here; merge kernel computes norms)
  const float scale = 2.0f / 512.0f;
  const int jF = (j == 32) ? 0 : j + 1;
#pragma unroll
  for (int tn = 0; tn < 4; ++tn) {
#pragma unroll
    for (int rq = 0; rq < 4; ++rq) {
      int band = w * 16 + quad * 4 + rq;
      float sc = (band == 0) ? scale * 0.5f : scale;
      int dd = d0 + tn * 16 + r16;
      if (j < 32) bufS[(j * 64 + band) * 2048 + dd] = accS[tn][rq] * sc;
      if (j != 31) bufF[(jF * 64 + band) * 2048 + dd] = accF[tn][rq] * sc;
    }
  }
}

// ---------------------------------------------------------------------------
// K1M: merge partials -> coeffs, and per-band norms. Grid (16, 32); one wave
// per band (4 bands/block), 2048 d streamed as float4.
// ---------------------------------------------------------------------------
__global__ __launch_bounds__(256) void k1m_merge(
    const float* __restrict__ bufS, const float* __restrict__ bufF,
    float* __restrict__ coeffs, float* __restrict__ norms)
{
  const int t = threadIdx.x, lane = t & 63, wv = t >> 6;
  const int kq = blockIdx.x;       // 0..15
  const int c  = blockIdx.y;       // 0..31
  const int k  = kq * 4 + wv;      // band owned by this wave
  const float* ps = bufS + (c * 64 + k) * 2048;
  const float* pf = bufF + (c * 64 + k) * 2048;
  float*       pc = coeffs + (c * 64 + k) * 2048;
  float ssum = 0.f;
#pragma unroll
  for (int i = 0; i < 8; ++i) {
    int d = lane * 4 + i * 256;
    float4 s = *(const float4*)(ps + d);
    float4 f = *(const float4*)(pf + d);
    float4 m = make_float4(s.x + f.x, s.y + f.y, s.z + f.z, s.w + f.w);
    *(float4*)(pc + d) = m;
    ssum += m.x * m.x + m.y * m.y + m.z * m.z + m.w * m.w;
  }
#pragma unroll
  for (int o = 32; o > 0; o >>= 1) ssum += __shfl_down(ssum, o, 64);
  if (lane == 0) norms[c * 64 + k] = fmaxf(sqrtf(ssum), 1e-12f);
}

// ---------------------------------------------------------------------------
// K2: bind (atomic vr/vi) + delta partials (atomic dsq); norms precomputed.
// grid (32, 32): bx -> xi=bx>>2 (d-chunk of 256), kg=bx&3 (16 bands); by=c.
// ---------------------------------------------------------------------------
__global__ __launch_bounds__(256) void k2_bind(
    const float* __restrict__ coeffs, const float* __restrict__ norms,
    const float* __restrict__ rr, const float* __restrict__ ri,
    float* __restrict__ vr, float* __restrict__ vi,
    float* __restrict__ dsq)
{
  __shared__ float inv_s[16];
  const int t = threadIdx.x, lane = t & 63;
  const int xi = blockIdx.x >> 2, kg = blockIdx.x & 3;
  const int c = blockIdx.y;
  if (t < 16) inv_s[t] = 1.0f / norms[c * 64 + kg * 16 + t];
  __syncthreads();
  const int d = xi * 256 + t;
  const float wc = 0.1f * powf(0.9f, (float)(31 - c));
  float ar = 0.f, ai = 0.f;
  if (c == 31) {
#pragma unroll
    for (int kk = 0; kk < 16; ++kk) {
      int k = kg * 16 + kk;
      float cf = coeffs[(31 * 64 + k) * 2048 + d];
      float cn = cf * inv_s[kk];
      ar += cn * rr[k * 2048 + d];
      ai += cn * ri[k * 2048 + d];
      float diff = cf - coeffs[(30 * 64 + k) * 2048 + d];
      float sqv = diff * diff;
#pragma unroll
      for (int o = 32; o > 0; o >>= 1) sqv += __shfl_down(sqv, o, 64);
      if (lane == 0) atomicAdd(&dsq[k], sqv);
    }
  } else {
#pragma unroll
    for (int kk = 0; kk < 16; ++kk) {
      int k = kg * 16 + kk;
      float cn = coeffs[(c * 64 + k) * 2048 + d] * inv_s[kk];
      ar += cn * rr[k * 2048 + d];
      ai += cn * ri[k * 2048 + d];
    }
  }
  atomicAdd(&vr[d], wc * ar);
  atomicAdd(&vi[d], wc * ai);
}

// ---------------------------------------------------------------------------
// K4: merged ctx+gemv. Per block: cn EMA + top-8 + ctx into LDS, then 4 gemv
// rows. Blocks 0..7 also emit delta/vr/vi outputs.
// ---------------------------------------------------------------------------
__global__ __launch_bounds__(256) void k4_gemv(
    const float* __restrict__ Wp, const float* __restrict__ norms,
    const float* __restrict__ dsq, const float* __restrict__ wb,
    const float* __restrict__ vr, const float* __restrict__ vi,
    const float* __restrict__ rr, const float* __restrict__ ri,
    const float* __restrict__ gate, float* __restrict__ dout)
{
  __shared__ float ctx_s[2048];
  __shared__ float cn_s[64];
  __shared__ int top_s[8];
  __shared__ float wgt_s[8];
  const int tid = threadIdx.x;
  const int lane = tid & 63;
  const int w = tid >> 6;

  if (tid < 64) {
    float s = 0.f;
    for (int c = 0; c < NCHUNK; ++c) s = 0.9f * s + 0.1f * norms[c * 64 + tid];
    cn_s[tid] = fmaxf(s, 1e-12f);
    if (blockIdx.x == 0) dout[D_MODEL + tid] = sqrtf(dsq[tid]);
  }
  if (tid == 0) {
    unsigned long long taken = 0ULL;
    for (int jj = 0; jj < 8; ++jj) {
      float best = -1.f;
      int bi = 0;
      for (int k = 0; k < 64; ++k) {
        float dv = dsq[k];              // sqrt monotone; compare pre-sqrt
        if (!((taken >> k) & 1ULL) && dv > best) { best = dv; bi = k; }
      }
      taken |= (1ULL << bi);
      top_s[jj] = bi;
      wgt_s[jj] = log1pf(expf(wb[bi]));  // softplus
    }
  }
  __syncthreads();

  // build ctx into LDS: 8 d per thread
  {
    const int d8 = tid * 8;
#pragma unroll
    for (int h = 0; h < 2; ++h) {
      const int d = d8 + h * 4;
      float4 v_r = *(const float4*)(vr + d);
      float4 v_i = *(const float4*)(vi + d);
      float4 cx = make_float4(0.f, 0.f, 0.f, 0.f);
#pragma unroll
      for (int jj = 0; jj < 8; ++jj) {
        int k = top_s[jj];
        float g = wgt_s[jj] * cn_s[k];
        float4 r = *(const float4*)(rr + k * D_MODEL + d);
        float4 im = *(const float4*)(ri + k * D_MODEL + d);
        cx.x += g * (v_r.x * r.x + v_i.x * im.x);
        cx.y += g * (v_r.y * r.y + v_i.y * im.y);
        cx.z += g * (v_r.z * r.z + v_i.z * im.z);
        cx.w += g * (v_r.w * r.w + v_i.w * im.w);
      }
      *(float4*)(ctx_s + d) = cx;
    }
  }
  if (blockIdx.x < 8) {
    const int d = blockIdx.x * 256 + tid;
    dout[D_MODEL + KB_ + d] = vr[d];
    dout[D_MODEL + KB_ + D_MODEL + d] = vi[d];
  }
  __syncthreads();

  const int row = blockIdx.x * 4 + w;
  const float* p = Wp + row * D_MODEL;
  float s = 0.f;
#pragma unroll
  for (int i = 0; i < 8; ++i) {
    int e = lane * 4 + i * 256;
    float4 wv = *(const float4*)(p + e);
    float4 cv = *(const float4*)(ctx_s + e);
    s += wv.x * cv.x + wv.y * cv.y + wv.z * cv.z + wv.w * cv.w;
  }
#pragma unroll
  for (int o = 32; o > 0; o >>= 1) s += __shfl_down(s, o, 64);
  if (lane == 0) {
    float sig = 1.f / (1.f + expf(-gate[0]));
    dout[row] = s * sig;
  }
}

extern "C" void kernel_launch(void* const* d_in, const int* in_sizes, int n_in,
                              void* d_out, int out_size, void* d_ws, size_t ws_size,
                              hipStream_t stream) {
  const float* scan  = (const float*)d_in[0];
  const float* buf   = (const float*)d_in[1];
  const float* rr    = (const float*)d_in[2];
  const float* ri    = (const float*)d_in[3];
  const float* wb    = (const float*)d_in[4];
  const float* Wp    = (const float*)d_in[5];
  const float* gate  = (const float*)d_in[6];
  const float* cheby = (const float*)d_in[7];
  float* out = (float*)d_out;
  float* ws = (float*)d_ws;

  float* bufS   = ws + OFF_S;
  float* bufF   = ws + OFF_F;
  float* coeffs = ws + OFF_C;
  float* norms  = ws + OFF_NORMS;
  float* vr     = ws + OFF_VR;
  float* vi     = ws + OFF_VI;
  float* dsq    = ws + OFF_DSQ;

  k1_part<<<dim3(32, 33), 256, 0, stream>>>(scan, buf, cheby, bufS, bufF, vr);
  k1m_merge<<<dim3(16, 32), 256, 0, stream>>>(bufS, bufF, coeffs, norms);
  k2_bind<<<dim3(32, 32), 256, 0, stream>>>(coeffs, norms, rr, ri, vr, vi, dsq);
  k4_gemv<<<512, 256, 0, stream>>>(Wp, norms, dsq, wb, vr, vi, rr, ri, gate, out);
}

// Round 10
// 271.129 us; speedup vs baseline: 1.0377x; 1.0377x over previous
//
#include <hip/hip_runtime.h>
#include <math.h>

#define D_MODEL 2048
#define KB_ 64
#define NCHUNK 32

typedef __bf16 bf16;
typedef __attribute__((ext_vector_type(8))) __bf16 bf16x8;
typedef __attribute__((ext_vector_type(4))) __bf16 bf16x4;
typedef __attribute__((ext_vector_type(4))) float f32x4;

// ---- workspace layout (float offsets) ----
#define OFF_COEFFS 0                            // [32][64][2048]
#define OFF_NSQ    (32 * 64 * 2048)             // [32][64][32]
#define OFF_NORMS  (OFF_NSQ + 32 * 64 * 32)     // [32][64]
#define OFF_VR     (OFF_NORMS + 2048)           // [2048]
#define OFF_VI     (OFF_VR + 2048)              // [2048]
#define OFF_DSQ    (OFF_VI + 2048)              // [64]  (vr|vi|dsq contiguous)
#define OFF_CTX    (OFF_DSQ + 64)               // [2048]

// ---------------------------------------------------------------------------
// K1: fused stage+GEMM. Block (dt, c): coeffs[c][band][d0..d0+64) =
//   scale * sum_n cheby[band][n] * mean(scan)[window_c n][d]
// Double-buffered LDS; loads for nb+1 issued before MFMAs of nb.
// Block (0,0) zeroes vr|vi|dsq for K2's atomics (safe: stream-ordered).
// ---------------------------------------------------------------------------
__device__ __forceinline__ void load_stage(
    const float* __restrict__ scan, const float* __restrict__ buf,
    int c, int nb, int n0, int dcol, float4* ra, float4* rb)
{
  if (c == 0 && nb < 4) {
    const float* bp = buf + (256 + nb * 64 + n0) * 2048 + dcol;
#pragma unroll
    for (int i = 0; i < 4; ++i) { ra[i] = *(const float4*)(bp + i * 2048); rb[i] = ra[i]; }
  } else {
    const float* p0 = scan + (c * 256 - 256 + nb * 64 + n0) * 2048 + dcol;
    const float* p1 = p0 + 8192 * 2048;
#pragma unroll
    for (int i = 0; i < 4; ++i) {
      ra[i] = *(const float4*)(p0 + i * 2048);
      rb[i] = *(const float4*)(p1 + i * 2048);
    }
  }
}

__device__ __forceinline__ void store_stage(
    bf16* Bsbuf, int n0, int d4, const float4* ra, const float4* rb)
{
  float4 m0 = make_float4(0.5f * (ra[0].x + rb[0].x), 0.5f * (ra[0].y + rb[0].y),
                          0.5f * (ra[0].z + rb[0].z), 0.5f * (ra[0].w + rb[0].w));
  float4 m1 = make_float4(0.5f * (ra[1].x + rb[1].x), 0.5f * (ra[1].y + rb[1].y),
                          0.5f * (ra[1].z + rb[1].z), 0.5f * (ra[1].w + rb[1].w));
  float4 m2 = make_float4(0.5f * (ra[2].x + rb[2].x), 0.5f * (ra[2].y + rb[2].y),
                          0.5f * (ra[2].z + rb[2].z), 0.5f * (ra[2].w + rb[2].w));
  float4 m3 = make_float4(0.5f * (ra[3].x + rb[3].x), 0.5f * (ra[3].y + rb[3].y),
                          0.5f * (ra[3].z + rb[3].z), 0.5f * (ra[3].w + rb[3].w));
  bf16x4 e0 = {(bf16)m0.x, (bf16)m1.x, (bf16)m2.x, (bf16)m3.x};
  bf16x4 e1 = {(bf16)m0.y, (bf16)m1.y, (bf16)m2.y, (bf16)m3.y};
  bf16x4 e2 = {(bf16)m0.z, (bf16)m1.z, (bf16)m2.z, (bf16)m3.z};
  bf16x4 e3 = {(bf16)m0.w, (bf16)m1.w, (bf16)m2.w, (bf16)m3.w};
  *(bf16x4*)(Bsbuf + (d4 + 0) * 72 + n0) = e0;
  *(bf16x4*)(Bsbuf + (d4 + 1) * 72 + n0) = e1;
  *(bf16x4*)(Bsbuf + (d4 + 2) * 72 + n0) = e2;
  *(bf16x4*)(Bsbuf + (d4 + 3) * 72 + n0) = e3;
}

__global__ __launch_bounds__(256, 4) void k1_fused(
    const float* __restrict__ scan, const float* __restrict__ buf,
    const float* __restrict__ cheby, float* __restrict__ coeffs,
    float* __restrict__ nsq, float* __restrict__ vzero)
{
  __shared__ bf16 Bs[2][64 * 72];

  const int t = threadIdx.x;
  const int dt = blockIdx.x;     // 0..31 d-tile
  const int c  = blockIdx.y;     // 0..31 window
  const int w = t >> 6, lane = t & 63;
  const int quad = lane >> 4, r16 = lane & 15;
  const int d0 = dt * 64;
  const int n0 = (t >> 4) * 4;
  const int d4 = (t & 15) * 4;
  const int dcol = d0 + d4;

  if (dt == 0 && c == 0) {
    for (int i = t; i < 4160; i += 256) vzero[i] = 0.f;   // vr | vi | dsq
  }

  f32x4 acc[4];
#pragma unroll
  for (int tn = 0; tn < 4; ++tn) acc[tn] = (f32x4){0.f, 0.f, 0.f, 0.f};

  float4 ra[4], rb[4];
  load_stage(scan, buf, c, 0, n0, dcol, ra, rb);
  store_stage(Bs[0], n0, d4, ra, rb);
  __syncthreads();

  for (int nb = 0; nb < 8; ++nb) {
    if (nb < 7) load_stage(scan, buf, c, nb + 1, n0, dcol, ra, rb);

    // A-fragments: f32 cheby (L2-resident) -> bf16 in-register
    const float* ab = cheby + (w * 16 + r16) * 512 + nb * 64 + quad * 8;
    float4 f0 = *(const float4*)(ab);
    float4 f1 = *(const float4*)(ab + 4);
    float4 f2 = *(const float4*)(ab + 32);
    float4 f3 = *(const float4*)(ab + 36);
    bf16x8 a0 = {(bf16)f0.x, (bf16)f0.y, (bf16)f0.z, (bf16)f0.w,
                 (bf16)f1.x, (bf16)f1.y, (bf16)f1.z, (bf16)f1.w};
    bf16x8 a1 = {(bf16)f2.x, (bf16)f2.y, (bf16)f2.z, (bf16)f2.w,
                 (bf16)f3.x, (bf16)f3.y, (bf16)f3.z, (bf16)f3.w};

    const bf16* bsr = Bs[nb & 1];
#pragma unroll
    for (int ks = 0; ks < 2; ++ks) {
      bf16x8 a = ks ? a1 : a0;
#pragma unroll
      for (int tn = 0; tn < 4; ++tn) {
        bf16x8 bfr = *(const bf16x8*)(bsr + (tn * 16 + r16) * 72 + ks * 32 + quad * 8);
        acc[tn] = __builtin_amdgcn_mfma_f32_16x16x32_bf16(a, bfr, acc[tn], 0, 0, 0);
      }
    }

    if (nb < 7) store_stage(Bs[(nb + 1) & 1], n0, d4, ra, rb);
    __syncthreads();
  }

  // epilogue: scale, store, per-band sumsq partial
  const float scale = 2.0f / 512.0f;
  float sq[4] = {0.f, 0.f, 0.f, 0.f};
#pragma unroll
  for (int tn = 0; tn < 4; ++tn) {
#pragma unroll
    for (int rq = 0; rq < 4; ++rq) {
      int band = w * 16 + quad * 4 + rq;
      float sc = (band == 0) ? scale * 0.5f : scale;
      float v = acc[tn][rq] * sc;
      coeffs[(c * 64 + band) * 2048 + d0 + tn * 16 + r16] = v;
      sq[rq] += v * v;
    }
  }
#pragma unroll
  for (int off = 8; off > 0; off >>= 1) {
#pragma unroll
    for (int rq = 0; rq < 4; ++rq) sq[rq] += __shfl_down(sq[rq], off);
  }
  if (r16 == 0) {
#pragma unroll
    for (int rq = 0; rq < 4; ++rq)
      nsq[(c * 64 + w * 16 + quad * 4 + rq) * 32 + dt] = sq[rq];
  }
}

// ---------------------------------------------------------------------------
// K2: norms + bind (atomic vr/vi) + delta partials (atomic dsq).
// grid (32, 32): bx -> xi=bx>>2 (d-chunk of 256), kg=bx&3 (16 bands); by=c.
// ---------------------------------------------------------------------------
__global__ __launch_bounds__(256) void k2_bind(
    const float* __restrict__ coeffs, const float* __restrict__ nsq,
    const float* __restrict__ rr, const float* __restrict__ ri,
    float* __restrict__ vr, float* __restrict__ vi,
    float* __restrict__ dsq, float* __restrict__ norms)
{
  __shared__ float inv_s[16];
  const int t = threadIdx.x, lane = t & 63;
  const int xi = blockIdx.x >> 2, kg = blockIdx.x & 3;
  const int c = blockIdx.y;
  if (t < 16) {
    int k = kg * 16 + t;
    float s = 0.f;
#pragma unroll
    for (int dtile = 0; dtile < 32; ++dtile) s += nsq[(c * 64 + k) * 32 + dtile];
    float nrm = fmaxf(sqrtf(s), 1e-12f);
    inv_s[t] = 1.0f / nrm;
    if (xi == 0) norms[c * 64 + k] = nrm;
  }
  __syncthreads();
  const int d = xi * 256 + t;
  const float wc = 0.1f * powf(0.9f, (float)(31 - c));
  float ar = 0.f, ai = 0.f;
  if (c == 31) {
    for (int kk = 0; kk < 16; ++kk) {
      int k = kg * 16 + kk;
      float cf = coeffs[(31 * 64 + k) * 2048 + d];
      float cn = cf * inv_s[kk];
      ar += cn * rr[k * 2048 + d];
      ai += cn * ri[k * 2048 + d];
      float diff = cf - coeffs[(30 * 64 + k) * 2048 + d];
      float sqv = diff * diff;
#pragma unroll
      for (int o = 32; o > 0; o >>= 1) sqv += __shfl_down(sqv, o, 64);
      if (lane == 0) atomicAdd(&dsq[k], sqv);
    }
  } else {
    for (int kk = 0; kk < 16; ++kk) {
      int k = kg * 16 + kk;
      float cn = coeffs[(c * 64 + k) * 2048 + d] * inv_s[kk];
      ar += cn * rr[k * 2048 + d];
      ai += cn * ri[k * 2048 + d];
    }
  }
  atomicAdd(&vr[d], wc * ar);
  atomicAdd(&vi[d], wc * ai);
}

// ---------------------------------------------------------------------------
// K3: cnorms EMA + top-8 (from dsq) + delta out + vr/vi out + ctx
// ---------------------------------------------------------------------------
__global__ __launch_bounds__(256) void k3_ctx(
    const float* __restrict__ norms, const float* __restrict__ vr,
    const float* __restrict__ vi, const float* __restrict__ rr,
    const float* __restrict__ ri, const float* __restrict__ wb,
    const float* __restrict__ dsq, float* __restrict__ dout,
    float* __restrict__ ctx)
{
  __shared__ float cn_s[64];
  __shared__ int top_s[8];
  __shared__ float wgt_s[8];
  const int t = threadIdx.x;
  const int d = blockIdx.x * 256 + t;
  if (t < 64) {
    float s = 0.f;
    for (int c = 0; c < NCHUNK; ++c) s = 0.9f * s + 0.1f * norms[c * 64 + t];
    cn_s[t] = fmaxf(s, 1e-12f);
    if (blockIdx.x == 0) dout[D_MODEL + t] = sqrtf(dsq[t]);
  }
  if (t == 0) {
    unsigned long long taken = 0ULL;
    for (int jj = 0; jj < 8; ++jj) {
      float best = -1.f;
      int bi = 0;
      for (int k = 0; k < 64; ++k) {
        float dv = dsq[k];          // sqrt monotone; compare pre-sqrt
        if (!((taken >> k) & 1ULL) && dv > best) { best = dv; bi = k; }
      }
      taken |= (1ULL << bi);
      top_s[jj] = bi;
      wgt_s[jj] = log1pf(expf(wb[bi]));  // softplus
    }
  }
  __syncthreads();
  float sr = vr[d], si = vi[d];
  dout[D_MODEL + KB_ + d] = sr;
  dout[D_MODEL + KB_ + D_MODEL + d] = si;
  float cx = 0.f;
#pragma unroll
  for (int jj = 0; jj < 8; ++jj) {
    int k = top_s[jj];
    cx += wgt_s[jj] * (sr * rr[k * D_MODEL + d] + si * ri[k * D_MODEL + d]) * cn_s[k];
  }
  ctx[d] = cx;
}

// K4: out[d] = sigmoid(gate) * sum_e ctx[e]*Wp[d][e]; one wave per row
__global__ __launch_bounds__(256) void k4_gemv(
    const float* __restrict__ Wp, const float* __restrict__ ctx,
    const float* __restrict__ gate, float* __restrict__ dout)
{
  const int tid = threadIdx.x;
  const int lane = tid & 63;
  const int w = tid >> 6;
  const int row = blockIdx.x * 4 + w;
  const float* p = Wp + row * D_MODEL;
  float s = 0.f;
#pragma unroll
  for (int i = 0; i < 8; ++i) {
    int e = lane * 4 + i * 256;
    float4 wv = *(const float4*)(p + e);
    float4 cv = *(const float4*)(ctx + e);
    s += wv.x * cv.x + wv.y * cv.y + wv.z * cv.z + wv.w * cv.w;
  }
#pragma unroll
  for (int o = 32; o > 0; o >>= 1) s += __shfl_down(s, o, 64);
  if (lane == 0) {
    float sig = 1.f / (1.f + expf(-gate[0]));
    dout[row] = s * sig;
  }
}

extern "C" void kernel_launch(void* const* d_in, const int* in_sizes, int n_in,
                              void* d_out, int out_size, void* d_ws, size_t ws_size,
                              hipStream_t stream) {
  const float* scan  = (const float*)d_in[0];
  const float* buf   = (const float*)d_in[1];
  const float* rr    = (const float*)d_in[2];
  const float* ri    = (const float*)d_in[3];
  const float* wb    = (const float*)d_in[4];
  const float* Wp    = (const float*)d_in[5];
  const float* gate  = (const float*)d_in[6];
  const float* cheby = (const float*)d_in[7];
  float* out = (float*)d_out;
  float* ws = (float*)d_ws;

  float* coeffs = ws + OFF_COEFFS;
  float* nsq    = ws + OFF_NSQ;
  float* norms  = ws + OFF_NORMS;
  float* vr     = ws + OFF_VR;
  float* vi     = ws + OFF_VI;
  float* dsq    = ws + OFF_DSQ;
  float* ctx    = ws + OFF_CTX;

  k1_fused<<<dim3(32, 32), 256, 0, stream>>>(scan, buf, cheby, coeffs, nsq, vr);
  k2_bind<<<dim3(32, 32), 256, 0, stream>>>(coeffs, nsq, rr, ri, vr, vi, dsq, norms);
  k3_ctx<<<8, 256, 0, stream>>>(norms, vr, vi, rr, ri, wb, dsq, out, ctx);
  k4_gemv<<<512, 256, 0, stream>>>(Wp, ctx, gate, out);
}